// Round 2
// baseline (250.458 us; speedup 1.0000x reference)
//
#include <hip/hip_runtime.h>
#include <hip/hip_bf16.h>
#include <stdint.h>

// Problem constants
#define KK 4
#define BB 16
#define LL 4096
#define DD 512
#define HH 128

typedef __attribute__((ext_vector_type(8))) short bf16x8;
typedef __attribute__((ext_vector_type(4))) float f32x4;
typedef __attribute__((ext_vector_type(4))) unsigned int u32x4;

__device__ __forceinline__ unsigned int pack_bf16(float lo, float hi) {
  unsigned int a = __float_as_uint(lo);
  unsigned int b = __float_as_uint(hi);
  a = (a + 0x7FFFu + ((a >> 16) & 1u)) >> 16;   // RNE f32->bf16
  b = (b + 0x7FFFu + ((b >> 16) & 1u)) >> 16;
  return a | (b << 16);
}

// ---------------- kernel 0a: q_bias = W_q @ vq + ln_b ----------------
__global__ void qbias_kernel(const float* __restrict__ ln_w,
                             const float* __restrict__ ln_b,
                             const float* __restrict__ vq,
                             float* __restrict__ qb) {
  int h = threadIdx.x;
  if (h < HH) {
    float acc = ln_b[h];
    const float* wq = ln_w + (size_t)h * (DD + HH) + DD;
    for (int j = 0; j < HH; ++j) acc = fmaf(wq[j], vq[j], acc);
    qb[h] = acc;
  }
}

// ---------------- kernel 0b: W_h -> fragment-ordered bf16 ----------------
// Chunk gid = (ks*8 + nt)*64 + lane holds 8 bf16 (B-fragment for MFMA):
//   element j (0..7): W[nt*16 + (lane&15)][ks*32 + (j>=4)*16 + (lane>>4)*4 + (j&3)]
// (d-within-32 permuted so that A-side global loads are 64B-contiguous per instr;
//  permutation applied identically on A and B sides -> contraction unchanged.)
__global__ void wf_kernel(const float* __restrict__ ln_w,
                          unsigned int* __restrict__ wf) {
  int gid = blockIdx.x * 256 + threadIdx.x;   // 0..8191
  int ks = gid >> 9;
  int nt = (gid >> 6) & 7;
  int lane = gid & 63;
  int h = nt * 16 + (lane & 15);
  int cg = lane >> 4;
  const float* src = ln_w + (size_t)h * (DD + HH) + ks * 32 + cg * 4;
  f32x4 v0 = *(const f32x4*)(src);
  f32x4 v1 = *(const f32x4*)(src + 16);
  u32x4 v;
  v.x = pack_bf16(v0.x, v0.y);
  v.y = pack_bf16(v0.z, v0.w);
  v.z = pack_bf16(v1.x, v1.y);
  v.w = pack_bf16(v1.z, v1.w);
  *(u32x4*)(wf + (size_t)gid * 4) = v;
}

// ---------------- main fused kernel: zero LDS, zero barriers ----------------
// Grid: 4096 blocks = (b, l-chunk of 16). Block: 256 threads = 4 independent
// waves; wave wv owns positions p0 = wv*4 .. +3 and ALL 4 k.
// MFMA A-tile rows r = k*4 + pos_off; lane l supplies row r = l&15,
// k-cols (l>>4)*8.. (d-permuted as above). C/D: col=lane&15, row=(lane>>4)*4+j
// -> lane group l>>4 = k, reg j = pos_off: softmax over k is shfl_xor 16/32.
__global__ __launch_bounds__(256, 2) void agg_main(
    const float* __restrict__ hs, const unsigned int* __restrict__ wf,
    const float* __restrict__ qb, const float* __restrict__ vw,
    float* __restrict__ out) {
  const int tid = threadIdx.x;
  const int lane = tid & 63;
  const int wv = tid >> 6;
  const int blk = blockIdx.x;
  const int b = blk >> 8;             // 256 l-chunks per b
  const int l0 = (blk & 255) << 4;
  const int p0 = wv << 2;

  const int r = lane & 15;            // MFMA A row
  const int kk = r >> 2;              // k-plane this lane loads
  const int pp = r & 3;               // position offset within wave
  const int cg = lane >> 4;           // col group

  // ---- phase 1: load + pack A fragments (hs read once, kept in regs) ----
  const float* abase =
      hs + (((size_t)kk * BB + b) * LL + (l0 + p0 + pp)) * DD + cg * 4;

  bf16x8 a_regs[16];
#pragma unroll
  for (int ks = 0; ks < 16; ++ks) {
    f32x4 v0 = *(const f32x4*)(abase + ks * 32);        // d = ks*32 + cg*4 + 0..3
    f32x4 v1 = *(const f32x4*)(abase + ks * 32 + 16);   // d = ks*32 + 16 + cg*4 + 0..3
    u32x4 p;
    p.x = pack_bf16(v0.x, v0.y);
    p.y = pack_bf16(v0.z, v0.w);
    p.z = pack_bf16(v1.x, v1.y);
    p.w = pack_bf16(v1.z, v1.w);
    a_regs[ks] = __builtin_bit_cast(bf16x8, p);
  }

  float qbr[8], vwr[8];
#pragma unroll
  for (int nt = 0; nt < 8; ++nt) {
    qbr[nt] = qb[nt * 16 + r];
    vwr[nt] = vw[nt * 16 + r];
  }

  // ---- phase 2: GEMM, W fragments streamed from L2 ----
  f32x4 acc[8];
#pragma unroll
  for (int nt = 0; nt < 8; ++nt) acc[nt] = (f32x4){0.f, 0.f, 0.f, 0.f};

#pragma unroll
  for (int ks = 0; ks < 16; ++ks) {
    bf16x8 wfv[8];
#pragma unroll
    for (int nt = 0; nt < 8; ++nt)
      wfv[nt] = *(const bf16x8*)(wf + ((ks * 8 + nt) * 64 + lane) * 4);
#pragma unroll
    for (int nt = 0; nt < 8; ++nt)
      acc[nt] = __builtin_amdgcn_mfma_f32_16x16x32_bf16(a_regs[ks], wfv[nt],
                                                        acc[nt], 0, 0, 0);
  }

  // ---- phase 3: scores + wave-local softmax over k ----
  // lane holds z[h = nt*16 + r][row=(lane>>4)*4+j] -> (k=lane>>4, pos=p0+j)
  float aw[4];
#pragma unroll
  for (int j = 0; j < 4; ++j) {
    float s = 0.f;
#pragma unroll
    for (int nt = 0; nt < 8; ++nt) {
      float z = acc[nt][j] + qbr[nt];
      z = fminf(15.f, fmaxf(-15.f, z));
      float e = __expf(-2.f * z);
      float th = (1.f - e) * __builtin_amdgcn_rcpf(1.f + e);
      s = fmaf(vwr[nt], th, s);
    }
    // reduce over h (16 lanes within group)
#pragma unroll
    for (int m = 1; m < 16; m <<= 1) s += __shfl_xor(s, m, 64);
    // softmax over k (across the 4 lane groups); mask is a uniform shift -> dropped
    float mx = fmaxf(s, __shfl_xor(s, 16, 64));
    mx = fmaxf(mx, __shfl_xor(mx, 32, 64));
    float e = __expf(s - mx);
    float den = e + __shfl_xor(e, 16, 64);
    den += __shfl_xor(den, 32, 64);
    aw[j] = e * __builtin_amdgcn_rcpf(den);   // a(k=lane>>4, pos=p0+j)
  }

  // redistribute: this lane's A rows belong to (k=kk, pos=pp)
  float av0 = __shfl(aw[0], kk << 4, 64);
  float av1 = __shfl(aw[1], kk << 4, 64);
  float av2 = __shfl(aw[2], kk << 4, 64);
  float av3 = __shfl(aw[3], kk << 4, 64);
  float av = pp == 0 ? av0 : (pp == 1 ? av1 : (pp == 2 ? av2 : av3));

  // ---- phase 4: weighted sum over k via shfl butterfly (bits 2,3 of lane) ----
  const bool wlane = (kk == 0);
  float* obase = out + (((size_t)b * LL + l0 + p0 + pp) * DD) + cg * 4;

#pragma unroll
  for (int ks = 0; ks < 16; ++ks) {
    u32x4 u = __builtin_bit_cast(u32x4, a_regs[ks]);
    float x[8];
    x[0] = av * __uint_as_float(u.x << 16);
    x[1] = av * __uint_as_float(u.x & 0xffff0000u);
    x[2] = av * __uint_as_float(u.y << 16);
    x[3] = av * __uint_as_float(u.y & 0xffff0000u);
    x[4] = av * __uint_as_float(u.z << 16);
    x[5] = av * __uint_as_float(u.z & 0xffff0000u);
    x[6] = av * __uint_as_float(u.w << 16);
    x[7] = av * __uint_as_float(u.w & 0xffff0000u);
#pragma unroll
    for (int j = 0; j < 8; ++j) {
      x[j] += __shfl_xor(x[j], 4, 64);
      x[j] += __shfl_xor(x[j], 8, 64);
    }
    if (wlane) {
      f32x4 o0 = {x[0], x[1], x[2], x[3]};
      f32x4 o1 = {x[4], x[5], x[6], x[7]};
      *(f32x4*)(obase + ks * 32) = o0;
      *(f32x4*)(obase + ks * 32 + 16) = o1;
    }
  }
}

extern "C" void kernel_launch(void* const* d_in, const int* in_sizes, int n_in,
                              void* d_out, int out_size, void* d_ws, size_t ws_size,
                              hipStream_t stream) {
  const float* hs   = (const float*)d_in[0];
  // d_in[1] = mask (int32) — unused: softmax over k is invariant to the
  // per-(b,l) uniform -1e4 shift, so the mask cannot affect x.
  const float* ln_w = (const float*)d_in[2];
  const float* ln_b = (const float*)d_in[3];
  const float* v_w  = (const float*)d_in[4];
  const float* vq   = (const float*)d_in[5];
  float* out = (float*)d_out;

  unsigned int* wf = (unsigned int*)d_ws;          // 128KB fragment-ordered bf16 W_h
  float* qb = (float*)((char*)d_ws + 131072);      // 512B q_bias

  qbias_kernel<<<1, 128, 0, stream>>>(ln_w, ln_b, vq, qb);
  wf_kernel<<<32, 256, 0, stream>>>(ln_w, wf);
  agg_main<<<4096, 256, 0, stream>>>(hs, wf, qb, v_w, out);
}